// Round 5
// baseline (1904.550 us; speedup 1.0000x reference)
//
#include <hip/hip_runtime.h>
#include <hip/hip_fp16.h>
#include <hip/hip_cooperative_groups.h>
#include <math.h>

namespace cg = cooperative_groups;

#define BN 1024      // batch
#define DIN 3072
#define DE 256
#define NK 6
#define KS 4         // critic split-K factor
#define KC (DIN / KS)
#define GBLK 384     // cooperative grid blocks (1.5/CU -- launch can't be rejected)
#define RPB 16       // rows per block = NK*BN/GBLK; 1024%16==0 -> no matrix straddle
#define MAXIT 20

constexpr float K2F = 14.4269504088896340736f;  // (1/eps)*log2(e), eps=0.1

// ---------------- critic GEMM (split-K partials) ----------------------------
__global__ __launch_bounds__(256) void critic_gemm(
    const float* __restrict__ x, const float* __restrict__ xp,
    const float* __restrict__ y, const float* __restrict__ yp,
    const float* __restrict__ Wc, float* __restrict__ Pp) {
  __shared__ float As[64][68];
  __shared__ float Bs[64][68];
  const int t = threadIdx.x;
  const int rt = blockIdx.x, ct = blockIdx.y, ks = blockIdx.z;
  const int R0 = rt * 64;
  const int m = R0 >> 10;
  const int r0 = R0 & 1023;
  const float* src = (m == 0) ? x : (m == 1) ? xp : (m == 2) ? y : yp;
  const int ty = t >> 4, tx = t & 15;

  float acc[4][4] = {};
  for (int kc0 = 0; kc0 < KC; kc0 += 64) {
    const int kc = ks * KC + kc0;
    __syncthreads();
#pragma unroll
    for (int i = 0; i < 4; ++i) {
      int r = (t >> 4) + 16 * i, q = t & 15;
      float4 av = *(const float4*)&src[(size_t)(r0 + r) * DIN + kc + 4 * q];
      As[4 * q + 0][r] = av.x; As[4 * q + 1][r] = av.y;
      As[4 * q + 2][r] = av.z; As[4 * q + 3][r] = av.w;
    }
#pragma unroll
    for (int i = 0; i < 4; ++i) {
      int k = t >> 2, cq = (t & 3) + 4 * i;
      float4 bv = *(const float4*)&Wc[(size_t)(kc + k) * DE + ct * 64 + 4 * cq];
      *(float4*)&Bs[k][4 * cq] = bv;
    }
    __syncthreads();
#pragma unroll 8
    for (int kk = 0; kk < 64; ++kk) {
      float4 a = *(const float4*)&As[kk][4 * ty];
      float4 b = *(const float4*)&Bs[kk][4 * tx];
      float av[4] = {a.x, a.y, a.z, a.w};
      float bv[4] = {b.x, b.y, b.z, b.w};
#pragma unroll
      for (int u = 0; u < 4; ++u)
#pragma unroll
        for (int v = 0; v < 4; ++v) acc[u][v] += av[u] * bv[v];
    }
  }
#pragma unroll
  for (int u = 0; u < 4; ++u) {
    int gi = R0 + ty * 4 + u;
    float4 o = {acc[u][0], acc[u][1], acc[u][2], acc[u][3]};
    *(float4*)&Pp[((size_t)ks * 4096 + gi) * DE + ct * 64 + 4 * tx] = o;
  }
}

// ---------------- combine split-K partials + bias + row-normalize -----------
__global__ __launch_bounds__(256) void critic_norm(
    const float* __restrict__ Pp, const float* __restrict__ bc,
    float* __restrict__ F) {
  __shared__ double red[4];
  __shared__ double nrm2s;
  const int row = blockIdx.x, t = threadIdx.x;
  double val = (double)bc[t];
#pragma unroll
  for (int ks = 0; ks < KS; ++ks)
    val += (double)Pp[((size_t)ks * 4096 + row) * DE + t];
  double ss = val * val;
#pragma unroll
  for (int off = 32; off; off >>= 1) ss += __shfl_down(ss, off);
  if ((t & 63) == 0) red[t >> 6] = ss;
  __syncthreads();
  if (t == 0) nrm2s = red[0] + red[1] + red[2] + red[3];
  __syncthreads();
  double rn = 1.0 / sqrt(nrm2s);
  F[(size_t)row * DE + t] = (float)(val * rn);
}

// ---------------- 6 cosine matrices -> Eh = exp(dot/eps) (fp16) + Eh^T ------
// Eh = e^{(1-C)/eps}; constant cost shift cancels in Sinkhorn (P invariant).
__global__ __launch_bounds__(256) void cosine_e(
    const float* __restrict__ F, __half* __restrict__ E, __half* __restrict__ ET) {
  __shared__ float As[64][68];
  __shared__ float Bs[64][68];
  const int pa[NK] = {0, 0, 1, 1, 0, 2};
  const int pb[NK] = {2, 3, 2, 3, 1, 3};
  const int p = blockIdx.z;
  const int ti = blockIdx.y, tj = blockIdx.x;
  const int t = threadIdx.x;
  const int ty = t >> 4, tx = t & 15;
  const float* FA = F + ((size_t)pa[p] * BN + ti * 64) * DE;
  const float* FB = F + ((size_t)pb[p] * BN + tj * 64) * DE;

  float acc[4][4] = {};
  for (int kc = 0; kc < DE; kc += 64) {
    __syncthreads();
#pragma unroll
    for (int i = 0; i < 4; ++i) {
      int r = (t >> 4) + 16 * i, q = t & 15;
      float4 av = *(const float4*)&FA[(size_t)r * DE + kc + 4 * q];
      As[4 * q + 0][r] = av.x; As[4 * q + 1][r] = av.y;
      As[4 * q + 2][r] = av.z; As[4 * q + 3][r] = av.w;
      float4 bv = *(const float4*)&FB[(size_t)r * DE + kc + 4 * q];
      Bs[4 * q + 0][r] = bv.x; Bs[4 * q + 1][r] = bv.y;
      Bs[4 * q + 2][r] = bv.z; Bs[4 * q + 3][r] = bv.w;
    }
    __syncthreads();
#pragma unroll 8
    for (int kk = 0; kk < 64; ++kk) {
      float4 a = *(const float4*)&As[kk][4 * ty];
      float4 b = *(const float4*)&Bs[kk][4 * tx];
      float av[4] = {a.x, a.y, a.z, a.w};
      float bv[4] = {b.x, b.y, b.z, b.w};
#pragma unroll
      for (int u = 0; u < 4; ++u)
#pragma unroll
        for (int v = 0; v < 4; ++v) acc[u][v] += av[u] * bv[v];
    }
  }
#pragma unroll
  for (int u = 0; u < 4; ++u) {
    union { __half h[4]; uint2 w; } pk;
#pragma unroll
    for (int v = 0; v < 4; ++v)
      pk.h[v] = __float2half(exp2f(acc[u][v] * K2F));
    int gi = ti * 64 + ty * 4 + u;
    *reinterpret_cast<uint2*>(&E[((((size_t)p << 10) + gi) << 10) + tj * 64 + 4 * tx]) = pk.w;
  }
#pragma unroll
  for (int v = 0; v < 4; ++v) {
    union { __half h[4]; uint2 w; } pk;
#pragma unroll
    for (int u = 0; u < 4; ++u)
      pk.h[u] = __float2half(exp2f(acc[u][v] * K2F));
    int gj = tj * 64 + tx * 4 + v;
    *reinterpret_cast<uint2*>(&ET[((((size_t)p << 10) + gj) << 10) + ti * 64 + 4 * ty]) = pk.w;
  }
}

// ================= shared Sinkhorn phase machinery ==========================
// fold4: reduce 4 per-lane f32 values across the 64-lane wave.
// Result: lane-group lg=lane>>4 holds total of row ((lg&1)<<1)|(lg>>1).
__device__ __forceinline__ float fold4(float s0, float s1, float s2, float s3,
                                       int lane) {
  float a01 = ((lane & 32) ? s1 : s0) + __shfl_xor(((lane & 32) ? s0 : s1), 32);
  float a23 = ((lane & 32) ? s3 : s2) + __shfl_xor(((lane & 32) ? s2 : s3), 32);
  float z = ((lane & 16) ? a23 : a01) + __shfl_xor(((lane & 16) ? a01 : a23), 16);
#pragma unroll
  for (int off = 8; off; off >>= 1) z += __shfl_xor(z, off);
  return z;
}

__device__ __forceinline__ void load_rows(const __half* M, int R0, int t,
                                          uint2 (&w)[RPB]) {
  const uint2* Mb = reinterpret_cast<const uint2*>(M) + ((size_t)R0 << 8);
#pragma unroll
  for (int r = 0; r < RPB; ++r) w[r] = Mb[(r << 8) + t];
}

// One half-step (WSUM=false): per-row partial dot(E_row, u) into red[64].
// WSUM=true: partial of sum_j E*u_j*C, C = 1 - eps*ln(E).
template <bool WSUM>
__device__ __forceinline__ void phase_rows(const uint2 (&w)[RPB], float4 uv,
                                           float* red, int t) {
  const int lane = t & 63, wv = t >> 6;
#pragma unroll
  for (int g = 0; g < 4; ++g) {
    float s[4];
#pragma unroll
    for (int r = 0; r < 4; ++r) {
      uint2 ww = w[g * 4 + r];
      float2 f0 = __half22float2(*reinterpret_cast<const __half2*>(&ww.x));
      float2 f1 = __half22float2(*reinterpret_cast<const __half2*>(&ww.y));
      if (WSUM) {
        s[r] = f0.x * uv.x * (1.f - 0.1f * __logf(f0.x)) +
               f0.y * uv.y * (1.f - 0.1f * __logf(f0.y)) +
               f1.x * uv.z * (1.f - 0.1f * __logf(f1.x)) +
               f1.y * uv.w * (1.f - 0.1f * __logf(f1.y));
      } else {
        s[r] = f0.x * uv.x + f0.y * uv.y + f1.x * uv.z + f1.y * uv.w;
      }
    }
    float z = fold4(s[0], s[1], s[2], s[3], lane);
    if ((lane & 15) == 0) {
      int lg = lane >> 4;
      int row = ((lg & 1) << 1) | (lg >> 1);
      red[wv * 16 + g * 4 + row] = z;
    }
  }
}

__device__ __forceinline__ void final_reduce(const double* Wp, float* out,
                                             int t, double* redf) {
  double p = 0.0;
  for (int i = t; i < GBLK; i += 256) p += Wp[i];
#pragma unroll
  for (int off = 32; off; off >>= 1) p += __shfl_down(p, off);
  if ((t & 63) == 0) redf[t >> 6] = p;
  __syncthreads();
  if (t == 0) out[0] = (float)(redf[0] + redf[1] + redf[2] + redf[3]);
}

// ---------------- fused cooperative Sinkhorn --------------------------------
__global__ __launch_bounds__(256, 2) void sinkhorn_fused(
    const __half* __restrict__ E, const __half* __restrict__ ET,
    float* __restrict__ uf, float* __restrict__ ug,
    double* __restrict__ Wp, float* __restrict__ out,
    const int* __restrict__ nit) {
  cg::grid_group grid = cg::this_grid();
  const int t = threadIdx.x, b = blockIdx.x;
  const int R0 = b * RPB, k = R0 >> 10;
  __shared__ float red[64];
  __shared__ double red2[RPB];
  __shared__ double redf[4];

  if (t < RPB) { uf[R0 + t] = 1.f; ug[R0 + t] = 1.f; }
  const int n = *nit;

  uint2 wE[RPB], wET[RPB];
  load_rows(E, R0, t, wE);
  load_rows(ET, R0, t, wET);

  const float4* ufk = reinterpret_cast<const float4*>(uf + (k << 10));
  const float4* ugk = reinterpret_cast<const float4*>(ug + (k << 10));
  grid.sync();

  for (int it = 0; it < n; ++it) {
    phase_rows<false>(wE, ugk[t], red, t);
    __syncthreads();
    if (t < RPB) {
      float S = red[t] + red[16 + t] + red[32 + t] + red[48 + t];
      uf[R0 + t] = 1.f / (1024.f * S);
    }
    grid.sync();
    phase_rows<false>(wET, ufk[t], red, t);
    __syncthreads();
    if (t < RPB) {
      float S = red[t] + red[16 + t] + red[32 + t] + red[48 + t];
      ug[R0 + t] = 1.f / (1024.f * S);
    }
    grid.sync();
  }

  phase_rows<true>(wE, ugk[t], red, t);
  __syncthreads();
  if (t < RPB)
    red2[t] = (double)(red[t] + red[16 + t] + red[32 + t] + red[48 + t]) *
              (double)uf[R0 + t];
  __syncthreads();
  if (t == 0) {
    double bp = 0.0;
#pragma unroll
    for (int r = 0; r < RPB; ++r) bp += red2[r];
    Wp[b] = ((k < 4) ? 1.0 : -2.0) * bp;
  }
  grid.sync();

  if (b == 0) final_reduce(Wp, out, t, redf);
}

// ---------------- fallback path (bit-identical math, 42 dispatches) ---------
__global__ __launch_bounds__(256) void fb_init(float* __restrict__ u) {
  int i = blockIdx.x * 256 + threadIdx.x;
  if (i < 2 * NK * BN) u[i] = 1.f;
}

__global__ __launch_bounds__(256) void fb_half(
    const __half* __restrict__ M, const float* __restrict__ uin,
    float* __restrict__ uout, int it, const int* __restrict__ nit) {
  if (it >= *nit) return;
  __shared__ float red[64];
  const int t = threadIdx.x, b = blockIdx.x;
  const int R0 = b * RPB, k = R0 >> 10;
  uint2 w[RPB];
  load_rows(M, R0, t, w);
  phase_rows<false>(w, reinterpret_cast<const float4*>(uin + (k << 10))[t], red, t);
  __syncthreads();
  if (t < RPB) {
    float S = red[t] + red[16 + t] + red[32 + t] + red[48 + t];
    uout[R0 + t] = 1.f / (1024.f * S);
  }
}

__global__ __launch_bounds__(256) void fb_wsum(
    const __half* __restrict__ E, const float* __restrict__ uf,
    const float* __restrict__ ug, double* __restrict__ Wp) {
  __shared__ float red[64];
  __shared__ double red2[RPB];
  const int t = threadIdx.x, b = blockIdx.x;
  const int R0 = b * RPB, k = R0 >> 10;
  uint2 w[RPB];
  load_rows(E, R0, t, w);
  phase_rows<true>(w, reinterpret_cast<const float4*>(ug + (k << 10))[t], red, t);
  __syncthreads();
  if (t < RPB)
    red2[t] = (double)(red[t] + red[16 + t] + red[32 + t] + red[48 + t]) *
              (double)uf[R0 + t];
  __syncthreads();
  if (t == 0) {
    double bp = 0.0;
#pragma unroll
    for (int r = 0; r < RPB; ++r) bp += red2[r];
    Wp[b] = ((k < 4) ? 1.0 : -2.0) * bp;
  }
}

__global__ __launch_bounds__(256) void fb_final(
    const double* __restrict__ Wp, float* __restrict__ out) {
  __shared__ double redf[4];
  final_reduce(Wp, out, threadIdx.x, redf);
}

extern "C" void kernel_launch(void* const* d_in, const int* in_sizes, int n_in,
                              void* d_out, int out_size, void* d_ws, size_t ws_size,
                              hipStream_t stream) {
  (void)in_sizes; (void)n_in; (void)out_size; (void)ws_size;
  const float* x  = (const float*)d_in[0];
  const float* xp = (const float*)d_in[1];
  const float* y  = (const float*)d_in[2];
  const float* yp = (const float*)d_in[3];
  const float* Wc = (const float*)d_in[4];
  const float* bc = (const float*)d_in[5];
  const int*  nit = (const int*)d_in[6];

  char* ws = (char*)d_ws;
  const size_t szEh = (size_t)NK * BN * BN * 2;          // 12.58 MB each
  __half* Eh  = (__half*)(ws);
  __half* EhT = (__half*)(ws + szEh);
  float*  F   = (float*)(ws + 2 * szEh);                 // 4.19 MB
  float*  uf  = (float*)(ws + 2 * szEh + (size_t)4 * BN * DE * 4);
  float*  ug  = uf + NK * BN;
  double* Wp  = (double*)(ug + NK * BN);                 // GBLK doubles
  float*  Pp  = (float*)(ws + (size_t)32 * 1024 * 1024); // 16.78 MB partials

  critic_gemm<<<dim3(64, 4, KS), 256, 0, stream>>>(x, xp, y, yp, Wc, Pp);
  critic_norm<<<4096, 256, 0, stream>>>(Pp, bc, F);
  cosine_e<<<dim3(16, 16, NK), 256, 0, stream>>>(F, Eh, EhT);

  const __half* Ehc  = Eh;
  const __half* EhTc = EhT;
  float* outp = (float*)d_out;
  const int* nitp = nit;
  void* args[] = {(void*)&Ehc, (void*)&EhTc, (void*)&uf, (void*)&ug,
                  (void*)&Wp, (void*)&outp, (void*)&nitp};
  hipError_t cerr = hipLaunchCooperativeKernel(
      reinterpret_cast<void*>(sinkhorn_fused), dim3(GBLK), dim3(256), args, 0,
      stream);
  if (cerr != hipSuccess) {
    // bit-identical fallback: same phase_rows/fold4 device code per dispatch
    fb_init<<<48, 256, 0, stream>>>(uf);
    for (int it = 0; it < MAXIT; ++it) {
      fb_half<<<GBLK, 256, 0, stream>>>(Eh, ug, uf, it, nit);
      fb_half<<<GBLK, 256, 0, stream>>>(EhT, uf, ug, it, nit);
    }
    fb_wsum<<<GBLK, 256, 0, stream>>>(Eh, uf, ug, Wp);
    fb_final<<<1, 256, 0, stream>>>(Wp, outp);
  }
}

// Round 6
// 272.810 us; speedup vs baseline: 6.9812x; 6.9812x over previous
//
#include <hip/hip_runtime.h>
#include <hip/hip_fp16.h>
#include <math.h>

#define BN 1024      // batch
#define DIN 3072
#define DE 256
#define NK 6
#define KS 4         // critic split-K factor
#define GBLK 384     // sinkhorn blocks
#define RPB 16       // rows per sinkhorn block
#define MAXIT 20
#define BM 128       // critic block tile rows
#define BNC 128      // critic block tile cols
#define KSTEP 32
#define LDA 40       // LDS row stride (elems) for 32 bf16 + pad (80B: 16B-aligned, 2-way banks)

constexpr float K2F = 14.4269504088896340736f;  // (1/eps)*log2(e), eps=0.1

typedef short short8 __attribute__((ext_vector_type(8)));
typedef float float4v __attribute__((ext_vector_type(4)));
typedef unsigned short ushort4v __attribute__((ext_vector_type(4)));

__device__ __forceinline__ unsigned short f2bf(float x) {  // RNE, no NaN path
  union { float f; unsigned u; } v; v.f = x;
  unsigned r = v.u + 0x7FFF + ((v.u >> 16) & 1);
  return (unsigned short)(r >> 16);
}
__device__ __forceinline__ float bf2f(unsigned short h) {
  union { float f; unsigned u; } v; v.u = ((unsigned)h) << 16;
  return v.f;
}

// ---------------- Wc -> WcT (256x3072) split into bf16 hi/lo ----------------
__global__ __launch_bounds__(256) void wct_prep(
    const float* __restrict__ Wc, unsigned short* __restrict__ WcTh,
    unsigned short* __restrict__ WcTl) {
  __shared__ float tile[64][65];
  const int t = threadIdx.x;
  const int kb = blockIdx.x * 64, cb = blockIdx.y * 64;
#pragma unroll
  for (int i = 0; i < 4; ++i) {
    int k = (t >> 4) + i * 16;
    int c = (t & 15) * 4;
    float4 v = *(const float4*)&Wc[(size_t)(kb + k) * DE + cb + c];
    tile[k][c] = v.x; tile[k][c + 1] = v.y; tile[k][c + 2] = v.z; tile[k][c + 3] = v.w;
  }
  __syncthreads();
#pragma unroll
  for (int i = 0; i < 4; ++i) {
    int c = (t >> 4) + i * 16;
    int k = (t & 15) * 4;
    ushort4v h, l;
#pragma unroll
    for (int j = 0; j < 4; ++j) {
      float v = tile[k + j][c];
      unsigned short hh = f2bf(v);
      h[j] = hh; l[j] = f2bf(v - bf2f(hh));
    }
    *(ushort4v*)&WcTh[(size_t)(cb + c) * DIN + kb + k] = h;
    *(ushort4v*)&WcTl[(size_t)(cb + c) * DIN + kb + k] = l;
  }
}

// ---------------- critic GEMM via bf16x2-split MFMA -------------------------
// grid (32 rowtiles, 2 coltiles, KS); block 256 = 4 waves of 64x64.
// dot = hi*hi + hi*lo + lo*hi  (lo*lo ~ 2^-18 rel, dropped)
__global__ __launch_bounds__(256) void critic_mfma(
    const float* __restrict__ x, const float* __restrict__ xp,
    const float* __restrict__ y, const float* __restrict__ yp,
    const unsigned short* __restrict__ WcTh,
    const unsigned short* __restrict__ WcTl, float* __restrict__ Pp) {
  __shared__ unsigned short Ah[BM][LDA], Al[BM][LDA];
  __shared__ unsigned short Bh[BNC][LDA], Bl[BNC][LDA];
  const int t = threadIdx.x;
  const int rt = blockIdx.x, ct = blockIdx.y, ks = blockIdx.z;
  const int R0 = rt * BM;              // 0..3968 (128 | 1024 -> no straddle)
  const int m = R0 >> 10, r0 = R0 & 1023;
  const float* src = (m == 0) ? x : (m == 1) ? xp : (m == 2) ? y : yp;
  const int wid = t >> 6, lane = t & 63;
  const int wy = wid >> 1, wx = wid & 1;
  const int fr = lane & 15, fg = lane >> 4;

  float4v acc[4][4];
#pragma unroll
  for (int i = 0; i < 4; ++i)
#pragma unroll
    for (int j = 0; j < 4; ++j) acc[i][j] = (float4v){0.f, 0.f, 0.f, 0.f};

  const int kbase = ks * (DIN / KS);
  for (int k0 = 0; k0 < DIN / KS; k0 += KSTEP) {
    const int kg = kbase + k0;
    __syncthreads();
    {  // stage A: 128 rows x 32 k (f32 -> bf16 hi/lo)
      int row = t >> 1, kq = (t & 1) * 16;
      const float* ap = src + (size_t)(r0 + row) * DIN + kg + kq;
      float4 a0 = *(const float4*)(ap);
      float4 a1 = *(const float4*)(ap + 4);
      float4 a2 = *(const float4*)(ap + 8);
      float4 a3 = *(const float4*)(ap + 12);
      float av[16] = {a0.x, a0.y, a0.z, a0.w, a1.x, a1.y, a1.z, a1.w,
                      a2.x, a2.y, a2.z, a2.w, a3.x, a3.y, a3.z, a3.w};
      short8 h0, h1, l0, l1;
#pragma unroll
      for (int j = 0; j < 8; ++j) {
        unsigned short h = f2bf(av[j]);
        h0[j] = (short)h; l0[j] = (short)f2bf(av[j] - bf2f(h));
        unsigned short g = f2bf(av[j + 8]);
        h1[j] = (short)g; l1[j] = (short)f2bf(av[j + 8] - bf2f(g));
      }
      *(short8*)&Ah[row][kq] = h0; *(short8*)&Ah[row][kq + 8] = h1;
      *(short8*)&Al[row][kq] = l0; *(short8*)&Al[row][kq + 8] = l1;
    }
    {  // stage B: 128 cols x 32 k from WcT hi/lo (already bf16)
      int col = t >> 1, kq = (t & 1) * 16;
      const unsigned short* bph = WcTh + (size_t)(ct * BNC + col) * DIN + kg + kq;
      const unsigned short* bpl = WcTl + (size_t)(ct * BNC + col) * DIN + kg + kq;
      short8 h0 = *(const short8*)(bph);
      short8 h1 = *(const short8*)(bph + 8);
      short8 l0 = *(const short8*)(bpl);
      short8 l1 = *(const short8*)(bpl + 8);
      *(short8*)&Bh[col][kq] = h0; *(short8*)&Bh[col][kq + 8] = h1;
      *(short8*)&Bl[col][kq] = l0; *(short8*)&Bl[col][kq + 8] = l1;
    }
    __syncthreads();
    short8 afh[4], afl[4], bfh[4], bfl[4];
#pragma unroll
    for (int i = 0; i < 4; ++i) {
      int row = wy * 64 + i * 16 + fr;
      afh[i] = *(const short8*)&Ah[row][fg * 8];
      afl[i] = *(const short8*)&Al[row][fg * 8];
      int col = wx * 64 + i * 16 + fr;
      bfh[i] = *(const short8*)&Bh[col][fg * 8];
      bfl[i] = *(const short8*)&Bl[col][fg * 8];
    }
#pragma unroll
    for (int i = 0; i < 4; ++i)
#pragma unroll
      for (int j = 0; j < 4; ++j) {
        acc[i][j] = __builtin_amdgcn_mfma_f32_16x16x32_bf16(afh[i], bfh[j], acc[i][j], 0, 0, 0);
        acc[i][j] = __builtin_amdgcn_mfma_f32_16x16x32_bf16(afh[i], bfl[j], acc[i][j], 0, 0, 0);
        acc[i][j] = __builtin_amdgcn_mfma_f32_16x16x32_bf16(afl[i], bfh[j], acc[i][j], 0, 0, 0);
      }
  }
  // C/D layout (m89-verified): col = lane&15, row = (lane>>4)*4 + reg
#pragma unroll
  for (int i = 0; i < 4; ++i)
#pragma unroll
    for (int j = 0; j < 4; ++j) {
      int grow = R0 + wy * 64 + i * 16 + fg * 4;
      int gcol = ct * BNC + wx * 64 + j * 16 + fr;
#pragma unroll
      for (int reg = 0; reg < 4; ++reg)
        Pp[((size_t)ks * 4096 + grow + reg) * DE + gcol] = acc[i][j][reg];
    }
}

// ---------------- combine split-K partials + bias + row-normalize -----------
__global__ __launch_bounds__(256) void critic_norm(
    const float* __restrict__ Pp, const float* __restrict__ bc,
    float* __restrict__ F) {
  __shared__ double red[4];
  __shared__ double nrm2s;
  const int row = blockIdx.x, t = threadIdx.x;
  double val = (double)bc[t];
#pragma unroll
  for (int ks = 0; ks < KS; ++ks)
    val += (double)Pp[((size_t)ks * 4096 + row) * DE + t];
  double ss = val * val;
#pragma unroll
  for (int off = 32; off; off >>= 1) ss += __shfl_down(ss, off);
  if ((t & 63) == 0) red[t >> 6] = ss;
  __syncthreads();
  if (t == 0) nrm2s = red[0] + red[1] + red[2] + red[3];
  __syncthreads();
  double rn = 1.0 / sqrt(nrm2s);
  F[(size_t)row * DE + t] = (float)(val * rn);
}

// ---------------- 6 cosine matrices -> Eh = exp(dot/eps) (fp16) + Eh^T ------
__global__ __launch_bounds__(256) void cosine_e(
    const float* __restrict__ F, __half* __restrict__ E, __half* __restrict__ ET) {
  __shared__ float As[64][68];
  __shared__ float Bs[64][68];
  const int pa[NK] = {0, 0, 1, 1, 0, 2};
  const int pb[NK] = {2, 3, 2, 3, 1, 3};
  const int p = blockIdx.z;
  const int ti = blockIdx.y, tj = blockIdx.x;
  const int t = threadIdx.x;
  const int ty = t >> 4, tx = t & 15;
  const float* FA = F + ((size_t)pa[p] * BN + ti * 64) * DE;
  const float* FB = F + ((size_t)pb[p] * BN + tj * 64) * DE;

  float acc[4][4] = {};
  for (int kc = 0; kc < DE; kc += 64) {
    __syncthreads();
#pragma unroll
    for (int i = 0; i < 4; ++i) {
      int r = (t >> 4) + 16 * i, q = t & 15;
      float4 av = *(const float4*)&FA[(size_t)r * DE + kc + 4 * q];
      As[4 * q + 0][r] = av.x; As[4 * q + 1][r] = av.y;
      As[4 * q + 2][r] = av.z; As[4 * q + 3][r] = av.w;
      float4 bv = *(const float4*)&FB[(size_t)r * DE + kc + 4 * q];
      Bs[4 * q + 0][r] = bv.x; Bs[4 * q + 1][r] = bv.y;
      Bs[4 * q + 2][r] = bv.z; Bs[4 * q + 3][r] = bv.w;
    }
    __syncthreads();
#pragma unroll 8
    for (int kk = 0; kk < 64; ++kk) {
      float4 a = *(const float4*)&As[kk][4 * ty];
      float4 b = *(const float4*)&Bs[kk][4 * tx];
      float av[4] = {a.x, a.y, a.z, a.w};
      float bv[4] = {b.x, b.y, b.z, b.w};
#pragma unroll
      for (int u = 0; u < 4; ++u)
#pragma unroll
        for (int v = 0; v < 4; ++v) acc[u][v] += av[u] * bv[v];
    }
  }
#pragma unroll
  for (int u = 0; u < 4; ++u) {
    union { __half h[4]; uint2 w; } pk;
#pragma unroll
    for (int v = 0; v < 4; ++v)
      pk.h[v] = __float2half(exp2f(acc[u][v] * K2F));
    int gi = ti * 64 + ty * 4 + u;
    *reinterpret_cast<uint2*>(&E[((((size_t)p << 10) + gi) << 10) + tj * 64 + 4 * tx]) = pk.w;
  }
#pragma unroll
  for (int v = 0; v < 4; ++v) {
    union { __half h[4]; uint2 w; } pk;
#pragma unroll
    for (int u = 0; u < 4; ++u)
      pk.h[u] = __float2half(exp2f(acc[u][v] * K2F));
    int gj = tj * 64 + tx * 4 + v;
    *reinterpret_cast<uint2*>(&ET[((((size_t)p << 10) + gj) << 10) + ti * 64 + 4 * ty]) = pk.w;
  }
}

// ================= Sinkhorn phase machinery (proven R5 fb path) =============
__device__ __forceinline__ float fold4(float s0, float s1, float s2, float s3,
                                       int lane) {
  float a01 = ((lane & 32) ? s1 : s0) + __shfl_xor(((lane & 32) ? s0 : s1), 32);
  float a23 = ((lane & 32) ? s3 : s2) + __shfl_xor(((lane & 32) ? s2 : s3), 32);
  float z = ((lane & 16) ? a23 : a01) + __shfl_xor(((lane & 16) ? a01 : a23), 16);
#pragma unroll
  for (int off = 8; off; off >>= 1) z += __shfl_xor(z, off);
  return z;
}

__device__ __forceinline__ void load_rows(const __half* M, int R0, int t,
                                          uint2 (&w)[RPB]) {
  const uint2* Mb = reinterpret_cast<const uint2*>(M) + ((size_t)R0 << 8);
#pragma unroll
  for (int r = 0; r < RPB; ++r) w[r] = Mb[(r << 8) + t];
}

template <bool WSUM>
__device__ __forceinline__ void phase_rows(const uint2 (&w)[RPB], float4 uv,
                                           float* red, int t) {
  const int lane = t & 63, wv = t >> 6;
#pragma unroll
  for (int g = 0; g < 4; ++g) {
    float s[4];
#pragma unroll
    for (int r = 0; r < 4; ++r) {
      uint2 ww = w[g * 4 + r];
      float2 f0 = __half22float2(*reinterpret_cast<const __half2*>(&ww.x));
      float2 f1 = __half22float2(*reinterpret_cast<const __half2*>(&ww.y));
      if (WSUM) {
        s[r] = f0.x * uv.x * (1.f - 0.1f * __logf(f0.x)) +
               f0.y * uv.y * (1.f - 0.1f * __logf(f0.y)) +
               f1.x * uv.z * (1.f - 0.1f * __logf(f1.x)) +
               f1.y * uv.w * (1.f - 0.1f * __logf(f1.y));
      } else {
        s[r] = f0.x * uv.x + f0.y * uv.y + f1.x * uv.z + f1.y * uv.w;
      }
    }
    float z = fold4(s[0], s[1], s[2], s[3], lane);
    if ((lane & 15) == 0) {
      int lg = lane >> 4;
      int row = ((lg & 1) << 1) | (lg >> 1);
      red[wv * 16 + g * 4 + row] = z;
    }
  }
}

__device__ __forceinline__ void final_reduce(const double* Wp, float* out,
                                             int t, double* redf) {
  double p = 0.0;
  for (int i = t; i < GBLK; i += 256) p += Wp[i];
#pragma unroll
  for (int off = 32; off; off >>= 1) p += __shfl_down(p, off);
  if ((t & 63) == 0) redf[t >> 6] = p;
  __syncthreads();
  if (t == 0) out[0] = (float)(redf[0] + redf[1] + redf[2] + redf[3]);
}

__global__ __launch_bounds__(256) void fb_init(float* __restrict__ u) {
  int i = blockIdx.x * 256 + threadIdx.x;
  if (i < 2 * NK * BN) u[i] = 1.f;
}

__global__ __launch_bounds__(256) void fb_half(
    const __half* __restrict__ M, const float* __restrict__ uin,
    float* __restrict__ uout, int it, const int* __restrict__ nit) {
  if (it >= *nit) return;
  __shared__ float red[64];
  const int t = threadIdx.x, b = blockIdx.x;
  const int R0 = b * RPB, k = R0 >> 10;
  uint2 w[RPB];
  load_rows(M, R0, t, w);
  phase_rows<false>(w, reinterpret_cast<const float4*>(uin + (k << 10))[t], red, t);
  __syncthreads();
  if (t < RPB) {
    float S = red[t] + red[16 + t] + red[32 + t] + red[48 + t];
    uout[R0 + t] = 1.f / (1024.f * S);
  }
}

__global__ __launch_bounds__(256) void fb_wsum(
    const __half* __restrict__ E, const float* __restrict__ uf,
    const float* __restrict__ ug, double* __restrict__ Wp) {
  __shared__ float red[64];
  __shared__ double red2[RPB];
  const int t = threadIdx.x, b = blockIdx.x;
  const int R0 = b * RPB, k = R0 >> 10;
  uint2 w[RPB];
  load_rows(E, R0, t, w);
  phase_rows<true>(w, reinterpret_cast<const float4*>(ug + (k << 10))[t], red, t);
  __syncthreads();
  if (t < RPB)
    red2[t] = (double)(red[t] + red[16 + t] + red[32 + t] + red[48 + t]) *
              (double)uf[R0 + t];
  __syncthreads();
  if (t == 0) {
    double bp = 0.0;
#pragma unroll
    for (int r = 0; r < RPB; ++r) bp += red2[r];
    Wp[b] = ((k < 4) ? 1.0 : -2.0) * bp;
  }
}

__global__ __launch_bounds__(256) void fb_final(
    const double* __restrict__ Wp, float* __restrict__ out) {
  __shared__ double redf[4];
  final_reduce(Wp, out, threadIdx.x, redf);
}

extern "C" void kernel_launch(void* const* d_in, const int* in_sizes, int n_in,
                              void* d_out, int out_size, void* d_ws, size_t ws_size,
                              hipStream_t stream) {
  (void)in_sizes; (void)n_in; (void)out_size; (void)ws_size;
  const float* x  = (const float*)d_in[0];
  const float* xp = (const float*)d_in[1];
  const float* y  = (const float*)d_in[2];
  const float* yp = (const float*)d_in[3];
  const float* Wc = (const float*)d_in[4];
  const float* bc = (const float*)d_in[5];
  const int*  nit = (const int*)d_in[6];

  char* ws = (char*)d_ws;
  const size_t szEh = (size_t)NK * BN * BN * 2;   // 12.58 MB each
  __half* Eh  = (__half*)(ws);
  __half* EhT = (__half*)(ws + szEh);
  float*  F   = (float*)(ws + 2 * szEh);          // 4.19 MB
  float*  uf  = (float*)(ws + 2 * szEh + (size_t)4 * BN * DE * 4);
  float*  ug  = uf + NK * BN;
  double* Wp  = (double*)(ug + NK * BN);          // GBLK doubles
  unsigned short* WcTh = (unsigned short*)(ws + 2 * szEh + (size_t)5 * 1024 * 1024);
  unsigned short* WcTl = WcTh + (size_t)DE * DIN; // 1.5 MB each
  // Pp (16.78 MB) aliases Eh + start of EhT: dead before cosine_e writes them
  float* Pp = (float*)(ws);

  wct_prep<<<dim3(DIN / 64, DE / 64), 256, 0, stream>>>(Wc, WcTh, WcTl);
  critic_mfma<<<dim3(4096 / BM, DE / BNC, KS), 256, 0, stream>>>(
      x, xp, y, yp, WcTh, WcTl, Pp);
  critic_norm<<<4096, 256, 0, stream>>>(Pp, bc, F);
  cosine_e<<<dim3(16, 16, NK), 256, 0, stream>>>(F, Eh, EhT);

  fb_init<<<48, 256, 0, stream>>>(uf);
  for (int it = 0; it < MAXIT; ++it) {
    fb_half<<<GBLK, 256, 0, stream>>>(Eh, ug, uf, it, nit);
    fb_half<<<GBLK, 256, 0, stream>>>(EhT, uf, ug, it, nit);
  }
  fb_wsum<<<GBLK, 256, 0, stream>>>(Eh, uf, ug, Wp);
  fb_final<<<1, 256, 0, stream>>>(Wp, (float*)d_out);
}